// Round 4
// baseline (13506.631 us; speedup 1.0000x reference)
//
#include <hip/hip_runtime.h>

// SymmetricRBM — round 9: 8 lanes/pair (4 waves/SIMD) + rolling-window LDS.
// Round-8 post-mortem: spill fix confirmed (VGPR 128, WRITE 1 MB, 1143 us).
// Remaining gap vs ~470 us VALU-issue floor attributed to latency at 2
// waves/SIMD (tf20 ~60-deep dep chains, ~120cy LDS latency) + LDS issue
// pressure. This round:
//  * pair split across 8 lanes (8 i's/thread): acc[2][4][8]=64 regs, grid
//    1024 blocks -> 4 waves/SIMD under __launch_bounds__(256,4).
//  * rolling 8-row float4 register window in G1/G2: rows for mm+1 overlap
//    7/8 with mm -> 1 ds_read_b128 per mm instead of 8 (8x fewer LDS reads).
//    mm unrolled by 8 so window slot (mmu-ii)&7 is compile-time constant.
//  * h/v mask exchange now 3 shfl_xor rounds (8->16->32->both words).
// RNG/counters/math unchanged -> bit-exact samples.

#define KSTEPS 10
#define HALF_H 8388608u   // (65536*4*64)/2
#define HALF_V 2097152u   // (65536*64)/2

__device__ __forceinline__ void tf20(unsigned int k0, unsigned int k1,
                                     unsigned int x0, unsigned int x1,
                                     unsigned int &o0, unsigned int &o1)
{
  unsigned int k2 = k0 ^ k1 ^ 0x1BD11BDAu;
  x0 += k0; x1 += k1;
#define TFR(rot) { x0 += x1; x1 = (x1 << (rot)) | (x1 >> (32 - (rot))); x1 ^= x0; }
  TFR(13) TFR(15) TFR(26) TFR(6)
  x0 += k1; x1 += k2 + 1u;
  TFR(17) TFR(29) TFR(16) TFR(24)
  x0 += k2; x1 += k0 + 2u;
  TFR(13) TFR(15) TFR(26) TFR(6)
  x0 += k0; x1 += k1 + 3u;
  TFR(17) TFR(29) TFR(16) TFR(24)
  x0 += k1; x1 += k2 + 4u;
  TFR(13) TFR(15) TFR(26) TFR(6)
  x0 += k2; x1 += k0 + 5u;
#undef TFR
  o0 = x0; o1 = x1;
}

__device__ __forceinline__ float u01(unsigned int bits) {
  return __uint_as_float((bits >> 9) | 0x3F800000u) - 1.0f;
}

__device__ __forceinline__ float softplusf(float x) {
  return fmaxf(x, 0.0f) + log1pf(expf(-fabsf(x)));
}

__global__ void init_ws_kernel(float* ws) { ws[0] = 0.0f; }

__global__ __launch_bounds__(256, 4)
void rbm_valu_kernel(const float* __restrict__ vdat,
                     const float* __restrict__ kf,
                     const float* __restrict__ bsp,
                     const float* __restrict__ cvp,
                     float* __restrict__ ws)
{
  // 4 staggered copies at 129-row stride (2064 B == 16 mod 128): q-groups
  // {q, q+4} share copy q&3; their rows differ by 32 (512 B == 0 mod 128)
  // -> at worst a free 2-way conflict (m136). Verified 0 conflicts at 4
  // copies in round 6/8.
  __shared__ __align__(16) float kd2[4][129][4];   // kd2[c][z][a] = kf[a*64+(z&63)]
  __shared__ unsigned int sK[4][KSTEPS];           // kh0,kh1,kv0,kv1 per step

  const int tid = threadIdx.x;                     // 0..255
  const int gthread = blockIdx.x * 256 + tid;      // 0..262143
  const int pair = gthread >> 3;                   // rows (pair, pair+32768)
  const int q = gthread & 7;                       // i-eighth
  const int i0 = 8 * q;
  const int c = q & 3;

  if (tid == 0) {
    unsigned int c0 = 0u, c1 = 42u;
    for (int t = 0; t < KSTEPS; ++t) {
      unsigned int Aa, Ab, Ba, Bb, Ca, Cb;
      tf20(c0, c1, 0u, 3u, Aa, Ab);
      tf20(c0, c1, 1u, 4u, Ba, Bb);
      tf20(c0, c1, 2u, 5u, Ca, Cb);
      sK[0][t] = Ca; sK[1][t] = Ab;   // kh
      sK[2][t] = Bb; sK[3][t] = Cb;   // kv
      c0 = Aa; c1 = Ba;               // next k
    }
  }
  for (int idx = tid; idx < 4 * 129; idx += 256) {
    const int cc = idx / 129;
    const int z = idx % 129;
    const int zz = z & 63;
    kd2[cc][z][0] = kf[zz];
    kd2[cc][z][1] = kf[64 + zz];
    kd2[cc][z][2] = kf[128 + zz];
    kd2[cc][z][3] = kf[192 + zz];
  }
  __syncthreads();

  const float4* kr = (const float4*)&kd2[c][0][0];   // kr[row] = 16B row

  // ---- load both rows of the pair as 2x32-bit masks each ----
  unsigned int vw[2][2];                           // [row][word]
  for (int r = 0; r < 2; ++r) {
    const float* vp = vdat + (size_t)(pair + r * 32768) * 64;
    unsigned int w0 = 0u, w1 = 0u;
#pragma unroll
    for (int j = 0; j < 32; j += 4) {
      float4 f = *(const float4*)(vp + j);
      w0 |= ((unsigned int)(f.x != 0.0f)) << (j + 0);
      w0 |= ((unsigned int)(f.y != 0.0f)) << (j + 1);
      w0 |= ((unsigned int)(f.z != 0.0f)) << (j + 2);
      w0 |= ((unsigned int)(f.w != 0.0f)) << (j + 3);
      float4 g = *(const float4*)(vp + 32 + j);
      w1 |= ((unsigned int)(g.x != 0.0f)) << (j + 0);
      w1 |= ((unsigned int)(g.y != 0.0f)) << (j + 1);
      w1 |= ((unsigned int)(g.z != 0.0f)) << (j + 2);
      w1 |= ((unsigned int)(g.w != 0.0f)) << (j + 3);
    }
    vw[r][0] = w0; vw[r][1] = w1;
  }

  const float bs = bsp[0];
  const float cv[4] = {cvp[0], cvp[1], cvp[2], cvp[3]};

  float fe = 0.0f;
  if (q == 0)   // term1 of fe_data, once per pair
    fe -= bs * (float)(__popc(vw[0][0]) + __popc(vw[0][1]) +
                       __popc(vw[1][0]) + __popc(vw[1][1]));

  unsigned int hw[2][2][4];   // [word][row][a] — full h masks after exchange

  for (int step = 0; step <= KSTEPS; ++step) {
    const bool fe_pass   = (step == KSTEPS);
    const bool data_pass = (step == 0);
    const unsigned int kh0 = sK[0][fe_pass ? 0 : step];
    const unsigned int kh1 = sK[1][fe_pass ? 0 : step];

    // ---- G1: acc[row][a][ii] += f_m * k[a][(m-i)&63], rolling window ----
    // row(ii, mm, w) = 32w + mm - (i0+ii) + 64 = base + mm - ii
    float acc[2][4][8] = {};
#pragma unroll
    for (int w = 0; w < 2; ++w) {
      unsigned int b0 = vw[0][w], b1 = vw[1][w];
      const int base = 32 * w - i0 + 64;
      float4 win[8];
#pragma unroll
      for (int s = 1; s < 8; ++s) win[s] = kr[base + s - 8];  // row base-(8-s)
      for (int mmo = 0; mmo < 32; mmo += 8) {
#pragma unroll
        for (int mmu = 0; mmu < 8; ++mmu) {
          win[mmu] = kr[base + mmo + mmu];      // new row base+mm
          float f0 = (float)(b0 & 1u); b0 >>= 1;
          float f1 = (float)(b1 & 1u); b1 >>= 1;
#pragma unroll
          for (int ii = 0; ii < 8; ++ii) {
            const float4 kv = win[(mmu - ii) & 7];   // row base+mm-ii
            acc[0][0][ii] += f0 * kv.x; acc[0][1][ii] += f0 * kv.y;
            acc[0][2][ii] += f0 * kv.z; acc[0][3][ii] += f0 * kv.w;
            acc[1][0][ii] += f1 * kv.x; acc[1][1][ii] += f1 * kv.y;
            acc[1][2][ii] += f1 * kv.z; acc[1][3][ii] += f1 * kv.w;
          }
        }
      }
    }

    if (fe_pass || data_pass) {   // term2 = -sum softplus(wv + c)
#pragma unroll
      for (int ii = 0; ii < 8; ++ii) {
        float s = 0.0f;
#pragma unroll
        for (int a = 0; a < 4; ++a) {
          float x0 = acc[0][a][ii] + cv[a];
          float x1 = acc[1][a][ii] + cv[a];
          s += softplusf(x0) + softplusf(x1);
        }
        fe += fe_pass ? s : -s;
      }
    }
    if (fe_pass) break;

    // ---- sample h for my 8 i's ----
    unsigned int hmy[2][4] = {{0u,0u,0u,0u},{0u,0u,0u,0u}};
#pragma unroll
    for (int ii = 0; ii < 8; ++ii) {
      const unsigned int base = (unsigned int)pair * 256u + (unsigned int)(i0 + ii);
#pragma unroll
      for (int a = 0; a < 4; ++a) {
        float x0 = acc[0][a][ii] + cv[a];
        float x1 = acc[1][a][ii] + cv[a];
        unsigned int cnt = base + (unsigned int)a * 64u;
        unsigned int r0, r1; tf20(kh0, kh1, cnt, cnt + HALF_H, r0, r1);
        float u0 = u01(r0), u1 = u01(r1);
        float e0 = __expf(-x0), e1 = __expf(-x1);
        hmy[0][a] |= ((fmaf(u0, e0, u0) < 1.0f) ? 1u : 0u) << ii;
        hmy[1][a] |= ((fmaf(u1, e1, u1) < 1.0f) ? 1u : 0u) << ii;
      }
    }

    // ---- exchange: assemble full 64-bit h masks across the 8 q-lanes ----
#pragma unroll
    for (int r = 0; r < 2; ++r)
#pragma unroll
      for (int a = 0; a < 4; ++a) {
        unsigned int my = hmy[r][a];
        unsigned int p1 = (unsigned int)__shfl_xor((int)my, 1);
        unsigned int v16 = (q & 1) ? (p1 | (my << 8)) : (my | (p1 << 8));
        unsigned int p2 = (unsigned int)__shfl_xor((int)v16, 2);
        unsigned int v32 = (q & 2) ? (p2 | (v16 << 16)) : (v16 | (p2 << 16));
        unsigned int p3 = (unsigned int)__shfl_xor((int)v32, 4);
        hw[0][r][a] = (q & 4) ? p3 : v32;
        hw[1][r][a] = (q & 4) ? v32 : p3;
      }

    // ---- G2: wh[row][ii] += sum_a f[a] * k[a][(i-1-m)&63], rolling window ----
    // row(ii, mm, w) = (i0+ii) + 63 - 32w - mm = base2 - mm + ii
    const unsigned int kv0 = sK[2][step], kv1 = sK[3][step];
    float wh[2][8] = {};
#pragma unroll
    for (int w = 0; w < 2; ++w) {
      unsigned int tA0 = hw[w][0][0], tA1 = hw[w][0][1];
      unsigned int tA2 = hw[w][0][2], tA3 = hw[w][0][3];
      unsigned int tB0 = hw[w][1][0], tB1 = hw[w][1][1];
      unsigned int tB2 = hw[w][1][2], tB3 = hw[w][1][3];
      const int base2 = i0 + 63 - 32 * w;
      float4 win[8];
#pragma unroll
      for (int s = 1; s < 8; ++s) win[s] = kr[base2 + 8 - s];  // row base2+(8-s)
      for (int mmo = 0; mmo < 32; mmo += 8) {
#pragma unroll
        for (int mmu = 0; mmu < 8; ++mmu) {
          win[mmu] = kr[base2 - mmo - mmu];     // new row base2-mm
          float fA0 = (float)(tA0 & 1u), fA1 = (float)(tA1 & 1u);
          float fA2 = (float)(tA2 & 1u), fA3 = (float)(tA3 & 1u);
          float fB0 = (float)(tB0 & 1u), fB1 = (float)(tB1 & 1u);
          float fB2 = (float)(tB2 & 1u), fB3 = (float)(tB3 & 1u);
#pragma unroll
          for (int ii = 0; ii < 8; ++ii) {
            const float4 kv = win[(mmu - ii) & 7];   // row base2-mm+ii
            wh[0][ii] += fA0 * kv.x + fA1 * kv.y + fA2 * kv.z + fA3 * kv.w;
            wh[1][ii] += fB0 * kv.x + fB1 * kv.y + fB2 * kv.z + fB3 * kv.w;
          }
          tA0 >>= 1; tA1 >>= 1; tA2 >>= 1; tA3 >>= 1;
          tB0 >>= 1; tB1 >>= 1; tB2 >>= 1; tB3 >>= 1;
        }
      }
    }

    // ---- sample v for my 8 i's ----
    unsigned int vmy[2] = {0u, 0u};
#pragma unroll
    for (int ii = 0; ii < 8; ++ii) {
      unsigned int cnt = (unsigned int)pair * 64u + (unsigned int)(i0 + ii);
      unsigned int r0, r1; tf20(kv0, kv1, cnt, cnt + HALF_V, r0, r1);
      float u0 = u01(r0), u1 = u01(r1);
      float e0 = __expf(-(wh[0][ii] + bs)), e1 = __expf(-(wh[1][ii] + bs));
      vmy[0] |= ((fmaf(u0, e0, u0) < 1.0f) ? 1u : 0u) << ii;
      vmy[1] |= ((fmaf(u1, e1, u1) < 1.0f) ? 1u : 0u) << ii;
    }

    // ---- exchange: assemble full v masks ----
#pragma unroll
    for (int r = 0; r < 2; ++r) {
      unsigned int my = vmy[r];
      unsigned int p1 = (unsigned int)__shfl_xor((int)my, 1);
      unsigned int v16 = (q & 1) ? (p1 | (my << 8)) : (my | (p1 << 8));
      unsigned int p2 = (unsigned int)__shfl_xor((int)v16, 2);
      unsigned int v32 = (q & 2) ? (p2 | (v16 << 16)) : (v16 | (p2 << 16));
      unsigned int p3 = (unsigned int)__shfl_xor((int)v32, 4);
      vw[r][0] = (q & 4) ? p3 : v32;
      vw[r][1] = (q & 4) ? v32 : p3;
    }
  }

  // term1 of fe_model, once per pair
  if (q == 0)
    fe += bs * (float)(__popc(vw[0][0]) + __popc(vw[0][1]) +
                       __popc(vw[1][0]) + __popc(vw[1][1]));

  // wave reduction, one atomic per wave
  for (int off = 32; off > 0; off >>= 1) fe += __shfl_down(fe, off);
  if ((tid & 63) == 0) atomicAdd(ws, fe);
}

__global__ void fin_kernel(const float* __restrict__ ws, float* __restrict__ out) {
  out[0] = ws[0] * (1.0f / 65536.0f);
}

extern "C" void kernel_launch(void* const* d_in, const int* in_sizes, int n_in,
                              void* d_out, int out_size, void* d_ws, size_t ws_size,
                              hipStream_t stream)
{
  (void)in_sizes; (void)n_in; (void)out_size; (void)ws_size;
  const float* vdat = (const float*)d_in[0];
  const float* kf   = (const float*)d_in[1];
  const float* bsp  = (const float*)d_in[2];
  const float* cvp  = (const float*)d_in[3];
  float* out = (float*)d_out;
  float* ws  = (float*)d_ws;

  init_ws_kernel<<<dim3(1), dim3(1), 0, stream>>>(ws);
  rbm_valu_kernel<<<dim3(1024), dim3(256), 0, stream>>>(vdat, kf, bsp, cvp, ws);
  fin_kernel<<<dim3(1), dim3(1), 0, stream>>>(ws, out);
}

// Round 5
// 1024.760 us; speedup vs baseline: 13.1803x; 13.1803x over previous
//
#include <hip/hip_runtime.h>

// SymmetricRBM — round 10: 8-i split + direct LDS loads + launch_bounds(256,2).
// Round-9 post-mortem: __launch_bounds__(256,4) made hipcc target the 64-VGPR
// (8 waves/SIMD) bin -> giant scratch spill (WRITE 32 GB), and under that
// pressure the mmu loop stopped unrolling so win[8] became runtime-indexed ->
// scratch/LDS (2.2e7 bank conflicts). Empirical rule: (256,2) -> 128-VGPR
// alloc, (256,4) -> 64. This round keeps round-9's parallelism win but drops
// both hazards:
//  * 8 lanes/pair (8 i's/thread): acc[2][4][8]=64 regs, demand ~110 -> fits
//    the 128-VGPR alloc that (256,2) empirically produces.
//  * grid 1024 blocks = 4 blocks/CU = 4 waves/SIMD (round-8 was grid-limited
//    to 2) -> 2x latency hiding for tf20 chains + LDS reads.
//  * direct kr[] float4 loads per (mm,ii), exactly round-8's pattern (no
//    rolling window).
// RNG/counters/FMA order unchanged -> bit-exact samples (round-9 layout
// already passed absmax 0.0).

#define KSTEPS 10
#define HALF_H 8388608u   // (65536*4*64)/2
#define HALF_V 2097152u   // (65536*64)/2

__device__ __forceinline__ void tf20(unsigned int k0, unsigned int k1,
                                     unsigned int x0, unsigned int x1,
                                     unsigned int &o0, unsigned int &o1)
{
  unsigned int k2 = k0 ^ k1 ^ 0x1BD11BDAu;
  x0 += k0; x1 += k1;
#define TFR(rot) { x0 += x1; x1 = (x1 << (rot)) | (x1 >> (32 - (rot))); x1 ^= x0; }
  TFR(13) TFR(15) TFR(26) TFR(6)
  x0 += k1; x1 += k2 + 1u;
  TFR(17) TFR(29) TFR(16) TFR(24)
  x0 += k2; x1 += k0 + 2u;
  TFR(13) TFR(15) TFR(26) TFR(6)
  x0 += k0; x1 += k1 + 3u;
  TFR(17) TFR(29) TFR(16) TFR(24)
  x0 += k1; x1 += k2 + 4u;
  TFR(13) TFR(15) TFR(26) TFR(6)
  x0 += k2; x1 += k0 + 5u;
#undef TFR
  o0 = x0; o1 = x1;
}

__device__ __forceinline__ float u01(unsigned int bits) {
  return __uint_as_float((bits >> 9) | 0x3F800000u) - 1.0f;
}

__device__ __forceinline__ float softplusf(float x) {
  return fmaxf(x, 0.0f) + log1pf(expf(-fabsf(x)));
}

__global__ void init_ws_kernel(float* ws) { ws[0] = 0.0f; }

__global__ __launch_bounds__(256, 2)
void rbm_valu_kernel(const float* __restrict__ vdat,
                     const float* __restrict__ kf,
                     const float* __restrict__ bsp,
                     const float* __restrict__ cvp,
                     float* __restrict__ ws)
{
  // 4 staggered copies at 129-row stride (2064 B == 16 mod 128). 8 q-groups
  // of 8 lanes; groups {q, q+4} share copy q&3 with rows 32 apart (512 B ==
  // 0 mod 128) -> 2-way bank aliasing, which is free (m136). Within a group
  // all 8 lanes read the same address -> broadcast.
  __shared__ __align__(16) float kd2[4][129][4];   // kd2[c][z][a] = kf[a*64+(z&63)]
  __shared__ unsigned int sK[4][KSTEPS];           // kh0,kh1,kv0,kv1 per step

  const int tid = threadIdx.x;                     // 0..255
  const int gthread = blockIdx.x * 256 + tid;      // 0..262143
  const int pair = gthread >> 3;                   // rows (pair, pair+32768)
  const int q = gthread & 7;                       // i-eighth
  const int i0 = 8 * q;
  const int c = q & 3;

  if (tid == 0) {
    unsigned int c0 = 0u, c1 = 42u;
    for (int t = 0; t < KSTEPS; ++t) {
      unsigned int Aa, Ab, Ba, Bb, Ca, Cb;
      tf20(c0, c1, 0u, 3u, Aa, Ab);
      tf20(c0, c1, 1u, 4u, Ba, Bb);
      tf20(c0, c1, 2u, 5u, Ca, Cb);
      sK[0][t] = Ca; sK[1][t] = Ab;   // kh
      sK[2][t] = Bb; sK[3][t] = Cb;   // kv
      c0 = Aa; c1 = Ba;               // next k
    }
  }
  for (int idx = tid; idx < 4 * 129; idx += 256) {
    const int cc = idx / 129;
    const int z = idx % 129;
    const int zz = z & 63;
    kd2[cc][z][0] = kf[zz];
    kd2[cc][z][1] = kf[64 + zz];
    kd2[cc][z][2] = kf[128 + zz];
    kd2[cc][z][3] = kf[192 + zz];
  }
  __syncthreads();

  const float4* kr = (const float4*)&kd2[c][0][0];   // kr[row] = 16B row

  // ---- load both rows of the pair as 2x32-bit masks each ----
  unsigned int vw[2][2];                           // [row][word]
  for (int r = 0; r < 2; ++r) {
    const float* vp = vdat + (size_t)(pair + r * 32768) * 64;
    unsigned int w0 = 0u, w1 = 0u;
#pragma unroll
    for (int j = 0; j < 32; j += 4) {
      float4 f = *(const float4*)(vp + j);
      w0 |= ((unsigned int)(f.x != 0.0f)) << (j + 0);
      w0 |= ((unsigned int)(f.y != 0.0f)) << (j + 1);
      w0 |= ((unsigned int)(f.z != 0.0f)) << (j + 2);
      w0 |= ((unsigned int)(f.w != 0.0f)) << (j + 3);
      float4 g = *(const float4*)(vp + 32 + j);
      w1 |= ((unsigned int)(g.x != 0.0f)) << (j + 0);
      w1 |= ((unsigned int)(g.y != 0.0f)) << (j + 1);
      w1 |= ((unsigned int)(g.z != 0.0f)) << (j + 2);
      w1 |= ((unsigned int)(g.w != 0.0f)) << (j + 3);
    }
    vw[r][0] = w0; vw[r][1] = w1;
  }

  const float bs = bsp[0];
  const float cv[4] = {cvp[0], cvp[1], cvp[2], cvp[3]};

  float fe = 0.0f;
  if (q == 0)   // term1 of fe_data, once per pair
    fe -= bs * (float)(__popc(vw[0][0]) + __popc(vw[0][1]) +
                       __popc(vw[1][0]) + __popc(vw[1][1]));

  unsigned int hw[2][2][4];   // [word][row][a] — full h masks after exchange

  for (int step = 0; step <= KSTEPS; ++step) {
    const bool fe_pass   = (step == KSTEPS);
    const bool data_pass = (step == 0);
    const unsigned int kh0 = sK[0][fe_pass ? 0 : step];
    const unsigned int kh1 = sK[1][fe_pass ? 0 : step];

    // ---- G1: acc[row][a][ii] += f_m * k[a][(m-i)&63] ----
    // row(ii, mm, w) = 32w + mm - (i0+ii) + 64 = base + mm - ii
    float acc[2][4][8] = {};
#pragma unroll
    for (int w = 0; w < 2; ++w) {
      unsigned int b0 = vw[0][w], b1 = vw[1][w];
      const int base = 32 * w - i0 + 64;
#pragma unroll 4
      for (int mm = 0; mm < 32; ++mm) {
        float f0 = (float)(b0 & 1u); b0 >>= 1;
        float f1 = (float)(b1 & 1u); b1 >>= 1;
        const float4* kp = kr + (base + mm);
#pragma unroll
        for (int ii = 0; ii < 8; ++ii) {
          const float4 kv = kp[-ii];             // row base+mm-ii
          acc[0][0][ii] += f0 * kv.x; acc[0][1][ii] += f0 * kv.y;
          acc[0][2][ii] += f0 * kv.z; acc[0][3][ii] += f0 * kv.w;
          acc[1][0][ii] += f1 * kv.x; acc[1][1][ii] += f1 * kv.y;
          acc[1][2][ii] += f1 * kv.z; acc[1][3][ii] += f1 * kv.w;
        }
      }
    }

    if (fe_pass || data_pass) {   // term2 = -sum softplus(wv + c)
#pragma unroll
      for (int ii = 0; ii < 8; ++ii) {
        float s = 0.0f;
#pragma unroll
        for (int a = 0; a < 4; ++a) {
          float x0 = acc[0][a][ii] + cv[a];
          float x1 = acc[1][a][ii] + cv[a];
          s += softplusf(x0) + softplusf(x1);
        }
        fe += fe_pass ? s : -s;
      }
    }
    if (fe_pass) break;

    // ---- sample h for my 8 i's ----
    unsigned int hmy[2][4] = {{0u,0u,0u,0u},{0u,0u,0u,0u}};
#pragma unroll
    for (int ii = 0; ii < 8; ++ii) {
      const unsigned int base = (unsigned int)pair * 256u + (unsigned int)(i0 + ii);
#pragma unroll
      for (int a = 0; a < 4; ++a) {
        float x0 = acc[0][a][ii] + cv[a];
        float x1 = acc[1][a][ii] + cv[a];
        unsigned int cnt = base + (unsigned int)a * 64u;
        unsigned int r0, r1; tf20(kh0, kh1, cnt, cnt + HALF_H, r0, r1);
        float u0 = u01(r0), u1 = u01(r1);
        float e0 = __expf(-x0), e1 = __expf(-x1);
        hmy[0][a] |= ((fmaf(u0, e0, u0) < 1.0f) ? 1u : 0u) << ii;
        hmy[1][a] |= ((fmaf(u1, e1, u1) < 1.0f) ? 1u : 0u) << ii;
      }
    }

    // ---- exchange: assemble full 64-bit h masks across the 8 q-lanes ----
#pragma unroll
    for (int r = 0; r < 2; ++r)
#pragma unroll
      for (int a = 0; a < 4; ++a) {
        unsigned int my = hmy[r][a];
        unsigned int p1 = (unsigned int)__shfl_xor((int)my, 1);
        unsigned int v16 = (q & 1) ? (p1 | (my << 8)) : (my | (p1 << 8));
        unsigned int p2 = (unsigned int)__shfl_xor((int)v16, 2);
        unsigned int v32 = (q & 2) ? (p2 | (v16 << 16)) : (v16 | (p2 << 16));
        unsigned int p3 = (unsigned int)__shfl_xor((int)v32, 4);
        hw[0][r][a] = (q & 4) ? p3 : v32;
        hw[1][r][a] = (q & 4) ? v32 : p3;
      }

    // ---- G2: wh[row][ii] += sum_a f[a] * k[a][(i-1-m)&63] ----
    // row(ii, mm, w) = (i0+ii) + 63 - 32w - mm = base2 - mm + ii
    const unsigned int kv0 = sK[2][step], kv1 = sK[3][step];
    float wh[2][8] = {};
#pragma unroll
    for (int w = 0; w < 2; ++w) {
      unsigned int tA0 = hw[w][0][0], tA1 = hw[w][0][1];
      unsigned int tA2 = hw[w][0][2], tA3 = hw[w][0][3];
      unsigned int tB0 = hw[w][1][0], tB1 = hw[w][1][1];
      unsigned int tB2 = hw[w][1][2], tB3 = hw[w][1][3];
      const int base2 = i0 + 63 - 32 * w;
#pragma unroll 4
      for (int mm = 0; mm < 32; ++mm) {
        float fA0 = (float)(tA0 & 1u), fA1 = (float)(tA1 & 1u);
        float fA2 = (float)(tA2 & 1u), fA3 = (float)(tA3 & 1u);
        float fB0 = (float)(tB0 & 1u), fB1 = (float)(tB1 & 1u);
        float fB2 = (float)(tB2 & 1u), fB3 = (float)(tB3 & 1u);
        const float4* kp = kr + (base2 - mm);
#pragma unroll
        for (int ii = 0; ii < 8; ++ii) {
          const float4 kv = kp[ii];              // row base2-mm+ii
          wh[0][ii] += fA0 * kv.x + fA1 * kv.y + fA2 * kv.z + fA3 * kv.w;
          wh[1][ii] += fB0 * kv.x + fB1 * kv.y + fB2 * kv.z + fB3 * kv.w;
        }
        tA0 >>= 1; tA1 >>= 1; tA2 >>= 1; tA3 >>= 1;
        tB0 >>= 1; tB1 >>= 1; tB2 >>= 1; tB3 >>= 1;
      }
    }

    // ---- sample v for my 8 i's ----
    unsigned int vmy[2] = {0u, 0u};
#pragma unroll
    for (int ii = 0; ii < 8; ++ii) {
      unsigned int cnt = (unsigned int)pair * 64u + (unsigned int)(i0 + ii);
      unsigned int r0, r1; tf20(kv0, kv1, cnt, cnt + HALF_V, r0, r1);
      float u0 = u01(r0), u1 = u01(r1);
      float e0 = __expf(-(wh[0][ii] + bs)), e1 = __expf(-(wh[1][ii] + bs));
      vmy[0] |= ((fmaf(u0, e0, u0) < 1.0f) ? 1u : 0u) << ii;
      vmy[1] |= ((fmaf(u1, e1, u1) < 1.0f) ? 1u : 0u) << ii;
    }

    // ---- exchange: assemble full v masks ----
#pragma unroll
    for (int r = 0; r < 2; ++r) {
      unsigned int my = vmy[r];
      unsigned int p1 = (unsigned int)__shfl_xor((int)my, 1);
      unsigned int v16 = (q & 1) ? (p1 | (my << 8)) : (my | (p1 << 8));
      unsigned int p2 = (unsigned int)__shfl_xor((int)v16, 2);
      unsigned int v32 = (q & 2) ? (p2 | (v16 << 16)) : (v16 | (p2 << 16));
      unsigned int p3 = (unsigned int)__shfl_xor((int)v32, 4);
      vw[r][0] = (q & 4) ? p3 : v32;
      vw[r][1] = (q & 4) ? v32 : p3;
    }
  }

  // term1 of fe_model, once per pair
  if (q == 0)
    fe += bs * (float)(__popc(vw[0][0]) + __popc(vw[0][1]) +
                       __popc(vw[1][0]) + __popc(vw[1][1]));

  // wave reduction, one atomic per wave
  for (int off = 32; off > 0; off >>= 1) fe += __shfl_down(fe, off);
  if ((tid & 63) == 0) atomicAdd(ws, fe);
}

__global__ void fin_kernel(const float* __restrict__ ws, float* __restrict__ out) {
  out[0] = ws[0] * (1.0f / 65536.0f);
}

extern "C" void kernel_launch(void* const* d_in, const int* in_sizes, int n_in,
                              void* d_out, int out_size, void* d_ws, size_t ws_size,
                              hipStream_t stream)
{
  (void)in_sizes; (void)n_in; (void)out_size; (void)ws_size;
  const float* vdat = (const float*)d_in[0];
  const float* kf   = (const float*)d_in[1];
  const float* bsp  = (const float*)d_in[2];
  const float* cvp  = (const float*)d_in[3];
  float* out = (float*)d_out;
  float* ws  = (float*)d_ws;

  init_ws_kernel<<<dim3(1), dim3(1), 0, stream>>>(ws);
  rbm_valu_kernel<<<dim3(1024), dim3(256), 0, stream>>>(vdat, kf, bsp, cvp, ws);
  fin_kernel<<<dim3(1), dim3(1), 0, stream>>>(ws, out);
}